// Round 2
// baseline (974.418 us; speedup 1.0000x reference)
//
#include <hip/hip_runtime.h>
#include <hip/hip_bf16.h>

using bf16 = __hip_bfloat16;
typedef __bf16 bf16x8_t __attribute__((ext_vector_type(8)));
typedef float f32x4_t __attribute__((ext_vector_type(4)));

#define SBAR() __builtin_amdgcn_s_barrier()
#define WAITV4() asm volatile("s_waitcnt vmcnt(4)" ::: "memory")
#define WAITLG() asm volatile("s_waitcnt lgkmcnt(0)" ::: "memory")
#define PRIO1() __builtin_amdgcn_s_setprio(1)
#define PRIO0() __builtin_amdgcn_s_setprio(0)

__device__ __forceinline__ void gload_lds16(const bf16* g, const bf16* l) {
  __builtin_amdgcn_global_load_lds(
      (const __attribute__((address_space(1))) void*)g,
      (__attribute__((address_space(3))) void*)l, 16, 0, 0);
}

// LDS layout: [buf][mat][khalf][row 0..255][slot 0..3 of 16B], swizzled:
// LDS(row,slot) holds global 16B-slot (slot ^ ((row>>1)&3)) of that row.
#define LOFF(buf, mat, kk) ((buf)*32768 + (mat)*16384 + (kk)*8192)

// ---------------- NT GEMM: C[m][n] = sum_k A[m][k] * B[n][k] ----------------
// 256x256 tile, BK=64, 8 waves, 8-phase counted-vmcnt schedule.
// EPI: 0 = bf16 out; 1 = f32 out * scale; 2 = f32 out + resid;
//      3 = bf16 out gelu(acc+bias); 4 = f32 out += (in-place) acc + bias
template <int EPI>
__launch_bounds__(512, 2)
__global__ void gemm_nt(const bf16* __restrict__ A, const bf16* __restrict__ B,
                        void* __restrict__ Cv, int K, int lda, int ldb, int ldc,
                        long long sA, long long sB, long long sC, float scale,
                        const float* __restrict__ bias,
                        const float* __restrict__ resid, long long sR, int ldr) {
  __shared__ __align__(16) bf16 smem[65536];  // 128 KiB
  const int tid = threadIdx.x;
  const int lane = tid & 63, wid = tid >> 6;
  const int wr = wid >> 2, wc = wid & 3;
  const int z = blockIdx.z;
  A += (size_t)z * sA;
  B += (size_t)z * sB;

  // T1: bijective XCD-aware block swizzle within the z-slice
  const int gx = gridDim.x, gy = gridDim.y;
  const int nwg = gx * gy;
  const int orig = blockIdx.x + gx * blockIdx.y;
  const int q = nwg >> 3, r = nwg & 7;
  const int xcd = orig & 7, loc = orig >> 3;
  const int wg = (xcd < r ? xcd * (q + 1) : r * (q + 1) + (xcd - r) * q) + loc;
  const int bm = (wg / gx) * 256;
  const int bn = (wg % gx) * 256;

  // ---- staging constants (global src pre-swizzled, LDS dest linear) ----
  const int srow = tid >> 2;                       // chunk row (and +128)
  const int sgsl = (tid & 3) ^ ((srow >> 1) & 3);  // swizzled source slot
  const bf16* gA0 = A + (size_t)(bm + srow) * lda + sgsl * 8;
  const bf16* gA1 = gA0 + (size_t)128 * lda;
  const bf16* gB0 = B + (size_t)(bn + srow) * ldb + sgsl * 8;
  const bf16* gB1 = gB0 + (size_t)128 * ldb;

#define STAGE_A(buf, kk, ke)                                   \
  {                                                            \
    const bf16* s_ = gA0 + (ke) + (kk) * 32;                   \
    const bf16* d_ = smem + LOFF(buf, 0, kk) + wid * 512;      \
    gload_lds16(s_, d_);                                       \
    gload_lds16(s_ + (size_t)128 * lda, d_ + 4096);            \
  }
#define STAGE_B(buf, kk, ke)                                   \
  {                                                            \
    const bf16* s_ = gB0 + (ke) + (kk) * 32;                   \
    const bf16* d_ = smem + LOFF(buf, 1, kk) + wid * 512;      \
    gload_lds16(s_, d_);                                       \
    gload_lds16(s_ + (size_t)128 * ldb, d_ + 4096);            \
  }

  // ---- fragment read constants (swizzled ds_read) ----
  const int gs = lane >> 4;
  const int rA = wr * 128 + (lane & 15);
  const int rB = wc * 64 + (lane & 15);
  const int eA = rA * 32 + ((gs ^ ((rA >> 1) & 3)) * 8);  // + mfrag*512
  const int eB = rB * 32 + ((gs ^ ((rB >> 1) & 3)) * 8);  // + nfrag*512

  f32x4_t acc[8][4] = {};
  bf16x8_t avb[4], bvb[4];

#define LOADA(buf, kk, mh)                                          \
  {                                                                 \
    const bf16* pA_ = smem + LOFF(buf, 0, kk) + eA + (mh) * 2048;   \
    _Pragma("unroll") for (int m_ = 0; m_ < 4; ++m_)                \
        avb[m_] = *(const bf16x8_t*)(pA_ + m_ * 512);               \
  }
#define LOADB(buf, kk)                                              \
  {                                                                 \
    const bf16* pB_ = smem + LOFF(buf, 1, kk) + eB;                 \
    _Pragma("unroll") for (int n_ = 0; n_ < 4; ++n_)                \
        bvb[n_] = *(const bf16x8_t*)(pB_ + n_ * 512);               \
  }
#define MM(mh)                                                      \
  _Pragma("unroll") for (int m_ = 0; m_ < 4; ++m_)                  \
      _Pragma("unroll") for (int n_ = 0; n_ < 4; ++n_)              \
          acc[(mh)*4 + m_][n_] = __builtin_amdgcn_mfma_f32_16x16x32_bf16( \
              avb[m_], bvb[n_], acc[(mh)*4 + m_][n_], 0, 0, 0);

  const int nt = K >> 6;   // K-tiles (even for all our shapes)
  const int km = nt - 1;   // nt is a power of two here
  const int nit = nt >> 1;

  // prologue: tile0 full (buf0) + tile1.k0 (buf1); 12 loads
  STAGE_A(0, 0, 0); STAGE_B(0, 0, 0);
  STAGE_A(0, 1, 0); STAGE_B(0, 1, 0);
  STAGE_A(1, 0, 64); STAGE_B(1, 0, 64);
  WAITV4();
  SBAR();

  for (int i = 0; i < nit; ++i) {
    const int ke1 = (2 * i + 1) * 64;
    const int ke2 = ((2 * i + 2) & km) * 64;  // wraps harmlessly on last iter
    const int ke3 = ((2 * i + 3) & km) * 64;
    // p1: tile0.k0 m0-3 + B.k0 | stage t1.A.k1
    LOADA(0, 0, 0); LOADB(0, 0);
    STAGE_A(1, 1, ke1);
    SBAR(); WAITLG(); PRIO1(); MM(0); PRIO0(); SBAR();
    // p2: tile0.k0 m4-7 | stage t1.B.k1
    LOADA(0, 0, 1);
    STAGE_B(1, 1, ke1);
    SBAR(); WAITLG(); PRIO1(); MM(1); PRIO0(); SBAR();
    // p3: tile0.k1 m0-3 + B.k1 | stage t2.A.k0
    LOADA(0, 1, 0); LOADB(0, 1);
    STAGE_A(0, 0, ke2);
    SBAR(); WAITLG(); PRIO1(); MM(0); PRIO0(); SBAR();
    // p4: tile0.k1 m4-7 | stage t2.B.k0 | vmcnt(4)
    LOADA(0, 1, 1);
    STAGE_B(0, 0, ke2);
    SBAR(); WAITLG(); PRIO1(); MM(1); PRIO0();
    WAITV4(); SBAR();
    // p5: tile1.k0 m0-3 + B.k0 | stage t2.A.k1
    LOADA(1, 0, 0); LOADB(1, 0);
    STAGE_A(0, 1, ke2);
    SBAR(); WAITLG(); PRIO1(); MM(0); PRIO0(); SBAR();
    // p6: tile1.k0 m4-7 | stage t2.B.k1
    LOADA(1, 0, 1);
    STAGE_B(0, 1, ke2);
    SBAR(); WAITLG(); PRIO1(); MM(1); PRIO0(); SBAR();
    // p7: tile1.k1 m0-3 + B.k1 | stage t3.A.k0
    LOADA(1, 1, 0); LOADB(1, 1);
    STAGE_A(1, 0, ke3);
    SBAR(); WAITLG(); PRIO1(); MM(0); PRIO0(); SBAR();
    // p8: tile1.k1 m4-7 | stage t3.B.k0 | vmcnt(4)
    LOADA(1, 1, 1);
    STAGE_B(1, 0, ke3);
    SBAR(); WAITLG(); PRIO1(); MM(1); PRIO0();
    WAITV4(); SBAR();
  }
  asm volatile("s_waitcnt vmcnt(0) lgkmcnt(0)" ::: "memory");
  SBAR();

  // ---- epilogue ----
  const int row0 = bm + wr * 128 + (lane >> 4) * 4;
  const int col0 = bn + wc * 64 + (lane & 15);
#pragma unroll
  for (int m = 0; m < 8; ++m) {
#pragma unroll
    for (int n = 0; n < 4; ++n) {
#pragma unroll
      for (int jj = 0; jj < 4; ++jj) {
        const int rr = row0 + m * 16 + jj;
        const int cc = col0 + n * 16;
        const float v = acc[m][n][jj];
        if constexpr (EPI == 0) {
          ((bf16*)Cv)[(size_t)z * sC + (size_t)rr * ldc + cc] = __float2bfloat16(v);
        } else if constexpr (EPI == 1) {
          ((float*)Cv)[(size_t)z * sC + (size_t)rr * ldc + cc] = v * scale;
        } else if constexpr (EPI == 2) {
          ((float*)Cv)[(size_t)z * sC + (size_t)rr * ldc + cc] =
              v + resid[(size_t)z * sR + (size_t)rr * ldr + cc];
        } else if constexpr (EPI == 3) {
          float t = v + bias[cc];
          float gl = 0.5f * t * (1.f + erff(t * 0.70710678118654752f));
          ((bf16*)Cv)[(size_t)z * sC + (size_t)rr * ldc + cc] = __float2bfloat16(gl);
        } else {
          float* Cf = (float*)Cv + (size_t)z * sC;
          const size_t idx = (size_t)rr * ldc + cc;
          Cf[idx] = Cf[idx] + v + bias[cc];
        }
      }
    }
  }
#undef STAGE_A
#undef STAGE_B
#undef LOADA
#undef LOADB
#undef MM
}

// ---------------- LayerNorm: fp32 in -> bf16 out, row length 1024 ----------
__global__ void ln_kernel(const float* __restrict__ X, const float* __restrict__ gw,
                          const float* __restrict__ bw, bf16* __restrict__ Y) {
  const int row = blockIdx.x, tid = threadIdx.x;
  const float4 xv = *(const float4*)(X + (size_t)row * 1024 + tid * 4);
  float s = xv.x + xv.y + xv.z + xv.w;
  float ss = xv.x * xv.x + xv.y * xv.y + xv.z * xv.z + xv.w * xv.w;
  __shared__ float red[8];
#pragma unroll
  for (int o = 32; o; o >>= 1) {
    s += __shfl_xor(s, o);
    ss += __shfl_xor(ss, o);
  }
  if ((tid & 63) == 0) {
    red[tid >> 6] = s;
    red[4 + (tid >> 6)] = ss;
  }
  __syncthreads();
  s = red[0] + red[1] + red[2] + red[3];
  ss = red[4] + red[5] + red[6] + red[7];
  const float mu = s * (1.f / 1024.f);
  const float var = ss * (1.f / 1024.f) - mu * mu;
  const float rs = rsqrtf(var + 1e-5f);
  const float4 gv = *(const float4*)(gw + tid * 4);
  const float4 bv = *(const float4*)(bw + tid * 4);
  union { ushort4 u; bf16 h[4]; } p;
  p.h[0] = __float2bfloat16((xv.x - mu) * rs * gv.x + bv.x);
  p.h[1] = __float2bfloat16((xv.y - mu) * rs * gv.y + bv.y);
  p.h[2] = __float2bfloat16((xv.z - mu) * rs * gv.z + bv.z);
  p.h[3] = __float2bfloat16((xv.w - mu) * rs * gv.w + bv.w);
  *(ushort4*)(Y + (size_t)row * 1024 + tid * 4) = p.u;
}

// ---------------- Softmax over rows of 2048 fp32 -> bf16 -------------------
__global__ void softmax_kernel(const float* __restrict__ S, bf16* __restrict__ P) {
  const size_t row = blockIdx.x;
  const int tid = threadIdx.x;
  const float4* sp = (const float4*)(S + row * 2048);
  const float4 v0 = sp[tid * 2], v1 = sp[tid * 2 + 1];
  float f[8] = {v0.x, v0.y, v0.z, v0.w, v1.x, v1.y, v1.z, v1.w};
  float m = f[0];
#pragma unroll
  for (int j = 1; j < 8; ++j) m = fmaxf(m, f[j]);
  __shared__ float red[4];
#pragma unroll
  for (int o = 32; o; o >>= 1) m = fmaxf(m, __shfl_xor(m, o));
  if ((tid & 63) == 0) red[tid >> 6] = m;
  __syncthreads();
  m = fmaxf(fmaxf(red[0], red[1]), fmaxf(red[2], red[3]));
  float s = 0.f;
#pragma unroll
  for (int j = 0; j < 8; ++j) {
    f[j] = expf(f[j] - m);
    s += f[j];
  }
#pragma unroll
  for (int o = 32; o; o >>= 1) s += __shfl_xor(s, o);
  __syncthreads();
  if ((tid & 63) == 0) red[tid >> 6] = s;
  __syncthreads();
  s = red[0] + red[1] + red[2] + red[3];
  const float inv = 1.f / s;
  union { uint4 u; bf16 h[8]; } p;
#pragma unroll
  for (int j = 0; j < 8; ++j) p.h[j] = __float2bfloat16(f[j] * inv);
  *(uint4*)(P + row * 2048 + tid * 8) = p.u;
}

// ------- Transpose + convert fp32 W[K][N] -> bf16 WT[rowoff+n][k] ----------
__global__ void transpose_conv(const float* __restrict__ W, bf16* __restrict__ WT,
                               int Nd, int ldT, int rowoff) {
  __shared__ float t[32][33];
  const int tx = threadIdx.x, ty = threadIdx.y;
  const int n0 = blockIdx.x * 32, k0 = blockIdx.y * 32;
#pragma unroll
  for (int j = 0; j < 4; ++j)
    t[ty + 8 * j][tx] = W[(size_t)(k0 + ty + 8 * j) * Nd + n0 + tx];
  __syncthreads();
#pragma unroll
  for (int j = 0; j < 4; ++j)
    WT[(size_t)(rowoff + n0 + ty + 8 * j) * ldT + k0 + tx] =
        __float2bfloat16(t[tx][ty + 8 * j]);
}

// ------- bf16 transpose: dst[c][r] = src[r][c], batched over z -------------
__global__ void transpose_bf16(const bf16* __restrict__ src, bf16* __restrict__ dst,
                               int ldsrc, int lddst, long long zs, long long zd) {
  __shared__ bf16 t[32][33];
  const int z = blockIdx.z;
  src += (size_t)z * zs;
  dst += (size_t)z * zd;
  const int tx = threadIdx.x, ty = threadIdx.y;
  const int c0 = blockIdx.x * 32, r0 = blockIdx.y * 32;
#pragma unroll
  for (int j = 0; j < 4; ++j)
    t[ty + 8 * j][tx] = src[(size_t)(r0 + ty + 8 * j) * ldsrc + c0 + tx];
  __syncthreads();
#pragma unroll
  for (int j = 0; j < 4; ++j)
    dst[(size_t)(c0 + ty + 8 * j) * lddst + r0 + tx] = t[tx][ty + 8 * j];
}

extern "C" void kernel_launch(void* const* d_in, const int* in_sizes, int n_in,
                              void* d_out, int out_size, void* d_ws, size_t ws_size,
                              hipStream_t stream) {
  const float* x = (const float*)d_in[0];
  const float* ln1_g = (const float*)d_in[1];
  const float* ln1_b = (const float*)d_in[2];
  const float* Wq = (const float*)d_in[3];
  const float* Wk = (const float*)d_in[4];
  const float* Wv = (const float*)d_in[5];
  const float* ln2_g = (const float*)d_in[6];
  const float* ln2_b = (const float*)d_in[7];
  const float* W1 = (const float*)d_in[8];
  const float* b1 = (const float*)d_in[9];
  const float* W2 = (const float*)d_in[10];
  const float* b2 = (const float*)d_in[11];
  float* out = (float*)d_out;

  constexpr int B = 8, N = 2048, H = 1024, F = 4096;
  constexpr int M = B * N;  // 16384

  const size_t WqkvTB = (size_t)3 * H * H * 2;
  const size_t W1TB = (size_t)H * F * 2;
  const size_t W2TB = (size_t)H * F * 2;
  const size_t yB = (size_t)M * H * 2;
  const size_t vTB = (size_t)M * H * 2;
  const size_t qkvB = (size_t)M * 3 * H * 2;
  const size_t SB1 = (size_t)N * N * 4;
  const size_t attB1 = (size_t)N * N * 2;
  const size_t hB = (size_t)M * F * 2;
  const size_t fixedB = WqkvTB + W1TB + W2TB + yB + vTB;

  int g = 8;
  for (; g > 1; g >>= 1) {
    size_t R = qkvB + (size_t)g * (SB1 + attB1);
    if (R < hB) R = hB;
    if (fixedB + R <= ws_size) break;
  }

  char* ws = (char*)d_ws;
  size_t o = 0;
  bf16* wqkvT = (bf16*)(ws + o); o += WqkvTB;
  bf16* w1T = (bf16*)(ws + o);   o += W1TB;
  bf16* w2T = (bf16*)(ws + o);   o += W2TB;
  bf16* y = (bf16*)(ws + o);     o += yB;
  bf16* vT = (bf16*)(ws + o);    o += vTB;
  char* Rb = ws + o;
  bf16* qkv = (bf16*)Rb;
  float* S = (float*)(Rb + qkvB);
  bf16* att = (bf16*)(Rb + qkvB + (size_t)g * SB1);
  bf16* h = (bf16*)Rb;  // overlays qkv/S/att after attention is done

  const dim3 tb(32, 8);
  // weight transpose+convert
  transpose_conv<<<dim3(H / 32, H / 32), tb, 0, stream>>>(Wq, wqkvT, H, H, 0);
  transpose_conv<<<dim3(H / 32, H / 32), tb, 0, stream>>>(Wk, wqkvT, H, H, H);
  transpose_conv<<<dim3(H / 32, H / 32), tb, 0, stream>>>(Wv, wqkvT, H, H, 2 * H);
  transpose_conv<<<dim3(F / 32, H / 32), tb, 0, stream>>>(W1, w1T, F, H, 0);
  transpose_conv<<<dim3(H / 32, F / 32), tb, 0, stream>>>(W2, w2T, H, F, 0);

  // LN1
  ln_kernel<<<M, 256, 0, stream>>>(x, ln1_g, ln1_b, y);

  // QKV projection: [M,H] @ WqkvT[3H,H]^T -> qkv [M,3H] bf16
  gemm_nt<0><<<dim3(3 * H / 256, M / 256, 1), 512, 0, stream>>>(
      y, wqkvT, qkv, H, H, H, 3 * H, 0, 0, 0, 1.f, nullptr, nullptr, 0, 0);

  // transpose V per batch: vT[b][d][m]
  transpose_bf16<<<dim3(H / 32, N / 32, B), tb, 0, stream>>>(
      qkv + 2 * H, vT, 3 * H, N, (long long)N * 3 * H, (long long)H * N);

  // attention in groups of g batches
  for (int b0 = 0; b0 < B; b0 += g) {
    const bf16* qb = qkv + (size_t)b0 * N * 3 * H;
    gemm_nt<1><<<dim3(N / 256, N / 256, g), 512, 0, stream>>>(
        qb, qb + H, S, H, 3 * H, 3 * H, N, (long long)N * 3 * H,
        (long long)N * 3 * H, (long long)N * N, 0.03125f, nullptr, nullptr, 0, 0);
    softmax_kernel<<<g * N, 256, 0, stream>>>(S, att);
    gemm_nt<2><<<dim3(H / 256, N / 256, g), 512, 0, stream>>>(
        att, vT + (size_t)b0 * H * N, out + (size_t)b0 * N * H, N, N, N, H,
        (long long)N * N, (long long)H * N, (long long)N * H, 1.f, nullptr,
        x + (size_t)b0 * N * H, (long long)N * H, H);
  }

  // LN2 on x2 (= d_out)
  ln_kernel<<<M, 256, 0, stream>>>(out, ln2_g, ln2_b, y);

  // FFN1: gelu(y @ W1 + b1) -> h bf16 [M,F]
  gemm_nt<3><<<dim3(F / 256, M / 256, 1), 512, 0, stream>>>(
      y, w1T, h, H, H, H, F, 0, 0, 0, 1.f, b1, nullptr, 0, 0);

  // FFN2: out += h @ W2 + b2 (in-place residual on d_out)
  gemm_nt<4><<<dim3(H / 256, M / 256, 1), 512, 0, stream>>>(
      h, w2T, out, F, F, F, H, 0, 0, 0, 1.f, b2, nullptr, 0, 0);
}

// Round 3
// 966.807 us; speedup vs baseline: 1.0079x; 1.0079x over previous
//
#include <hip/hip_runtime.h>
#include <hip/hip_bf16.h>

using bf16 = __hip_bfloat16;
typedef __bf16 bf16x8_t __attribute__((ext_vector_type(8)));
typedef float f32x4_t __attribute__((ext_vector_type(4)));

#define SBAR() __builtin_amdgcn_s_barrier()
#define WAITV6() asm volatile("s_waitcnt vmcnt(6)" ::: "memory")
#define WAITLG() asm volatile("s_waitcnt lgkmcnt(0)" ::: "memory")
#define PRIO1() __builtin_amdgcn_s_setprio(1)
#define PRIO0() __builtin_amdgcn_s_setprio(0)

__device__ __forceinline__ void gload_lds16(const bf16* g, const bf16* l) {
  __builtin_amdgcn_global_load_lds(
      (const __attribute__((address_space(1))) void*)g,
      (__attribute__((address_space(3))) void*)l, 16, 0, 0);
}

// exact-GELU via A&S 7.1.26 erf (|err| < 1.5e-7): ~12 VALU + v_exp
__device__ __forceinline__ float gelu_erf(float t) {
  const float ax = fabsf(t) * 0.70710678118654752f;
  const float u = 1.0f / fmaf(0.3275911f, ax, 1.0f);
  float p = fmaf(1.061405429f, u, -1.453152027f);
  p = fmaf(p, u, 1.421413741f);
  p = fmaf(p, u, -0.284496736f);
  p = fmaf(p, u, 0.254829592f);
  p = p * u * __expf(-ax * ax);
  float er = 1.0f - p;
  er = (t < 0.f) ? -er : er;
  return 0.5f * t * (1.0f + er);
}

// LDS layout: [buf][mat][khalf][row 0..255][slot 0..3 of 16B], swizzled:
// LDS(row,slot) holds global 16B-slot (slot ^ ((row>>1)&3)) of that row.
#define LOFF(buf, mat, kk) ((buf)*32768 + (mat)*16384 + (kk)*8192)

// ---------------- NT GEMM: C[m][n] = sum_k A[m][k] * B[n][k] ----------------
// 256x256 tile, BK=64, 8 waves, 8-phase schedule, depth-3 counted vmcnt(6).
// EPI: 0 = bf16 out; 1 = f32 out * scale; 2 = f32 out + resid;
//      3 = bf16 out gelu(acc+bias); 4 = f32 out += (in-place) acc + bias
template <int EPI>
__launch_bounds__(512, 2)
__global__ void gemm_nt(const bf16* __restrict__ A, const bf16* __restrict__ B,
                        void* __restrict__ Cv, int K, int lda, int ldb, int ldc,
                        long long sA, long long sB, long long sC, float scale,
                        const float* __restrict__ bias,
                        const float* __restrict__ resid, long long sR, int ldr) {
  __shared__ __align__(16) bf16 smem[65536];  // 128 KiB
  const int tid = threadIdx.x;
  const int lane = tid & 63, wid = tid >> 6;
  const int wr = wid >> 2, wc = wid & 3;
  const int z = blockIdx.z;
  A += (size_t)z * sA;
  B += (size_t)z * sB;

  // T1: bijective XCD-aware block swizzle within the z-slice
  const int gx = gridDim.x, gy = gridDim.y;
  const int nwg = gx * gy;
  const int orig = blockIdx.x + gx * blockIdx.y;
  const int q = nwg >> 3, r = nwg & 7;
  const int xcd = orig & 7, loc = orig >> 3;
  const int wg = (xcd < r ? xcd * (q + 1) : r * (q + 1) + (xcd - r) * q) + loc;
  const int bm = (wg / gx) * 256;
  const int bn = (wg % gx) * 256;

  // ---- staging constants (global src pre-swizzled, LDS dest linear) ----
  const int srow = tid >> 2;                       // chunk row (and +128)
  const int sgsl = (tid & 3) ^ ((srow >> 1) & 3);  // swizzled source slot
  const bf16* gA0 = A + (size_t)(bm + srow) * lda + sgsl * 8;
  const bf16* gB0 = B + (size_t)(bn + srow) * ldb + sgsl * 8;

#define STAGE_A(buf, kk, ke)                                   \
  {                                                            \
    const bf16* s_ = gA0 + (ke) + (kk) * 32;                   \
    const bf16* d_ = smem + LOFF(buf, 0, kk) + wid * 512;      \
    gload_lds16(s_, d_);                                       \
    gload_lds16(s_ + (size_t)128 * lda, d_ + 4096);            \
  }
#define STAGE_B(buf, kk, ke)                                   \
  {                                                            \
    const bf16* s_ = gB0 + (ke) + (kk) * 32;                   \
    const bf16* d_ = smem + LOFF(buf, 1, kk) + wid * 512;      \
    gload_lds16(s_, d_);                                       \
    gload_lds16(s_ + (size_t)128 * ldb, d_ + 4096);            \
  }

  // ---- fragment read constants (swizzled ds_read) ----
  const int gs = lane >> 4;
  const int rA = wr * 128 + (lane & 15);
  const int rB = wc * 64 + (lane & 15);
  const int eA = rA * 32 + ((gs ^ ((rA >> 1) & 3)) * 8);  // + mfrag*512
  const int eB = rB * 32 + ((gs ^ ((rB >> 1) & 3)) * 8);  // + nfrag*512

  f32x4_t acc[8][4] = {};
  bf16x8_t avb[4], bvb[4];

#define LOADA(buf, kk, mh)                                          \
  {                                                                 \
    const bf16* pA_ = smem + LOFF(buf, 0, kk) + eA + (mh) * 2048;   \
    _Pragma("unroll") for (int m_ = 0; m_ < 4; ++m_)                \
        avb[m_] = *(const bf16x8_t*)(pA_ + m_ * 512);               \
  }
#define LOADB(buf, kk)                                              \
  {                                                                 \
    const bf16* pB_ = smem + LOFF(buf, 1, kk) + eB;                 \
    _Pragma("unroll") for (int n_ = 0; n_ < 4; ++n_)                \
        bvb[n_] = *(const bf16x8_t*)(pB_ + n_ * 512);               \
  }
#define MM(mh)                                                      \
  _Pragma("unroll") for (int m_ = 0; m_ < 4; ++m_)                  \
      _Pragma("unroll") for (int n_ = 0; n_ < 4; ++n_)              \
          acc[(mh)*4 + m_][n_] = __builtin_amdgcn_mfma_f32_16x16x32_bf16( \
              avb[m_], bvb[n_], acc[(mh)*4 + m_][n_], 0, 0, 0);

  const int nt = K >> 6;   // K-tiles (power of two for all our shapes)
  const int km = nt - 1;
  const int nit = nt >> 1;

  // prologue: t0 full (8 loads) + t1.{B.k0, A.k0, B.k1} (6 loads, FIFO order
  // matching steady state p6,p7,p8); vmcnt(6) -> t0 resident, 6 in flight.
  STAGE_A(0, 0, 0); STAGE_B(0, 0, 0);
  STAGE_A(0, 1, 0); STAGE_B(0, 1, 0);
  STAGE_B(1, 0, 64); STAGE_A(1, 0, 64); STAGE_B(1, 1, 64);
  WAITV6();
  SBAR();

  for (int i = 0; i < nit; ++i) {
    const int ke1 = (2 * i + 1) * 64;
    const int ke2 = ((2 * i + 2) & km) * 64;  // wraps harmlessly on tail
    const int ke3 = ((2 * i + 3) & km) * 64;
    // p1: read t0.k0 (A m0-3, B) | stage t1.A.k1 (last read prev p7/p8)
    LOADA(0, 0, 0); LOADB(0, 0);
    STAGE_A(1, 1, ke1);
    SBAR(); WAITLG(); PRIO1(); MM(0); PRIO0(); SBAR();
    // p2: read t0.k0 A m4-7 | stage t2.B.k0 (last read p1)
    LOADA(0, 0, 1);
    STAGE_B(0, 0, ke2);
    SBAR(); WAITLG(); PRIO1(); MM(1); PRIO0(); SBAR();
    // p3: read t0.k1 (A m0-3, B) | stage t2.A.k0 (last read p2)
    LOADA(0, 1, 0); LOADB(0, 1);
    STAGE_A(0, 0, ke2);
    SBAR(); WAITLG(); PRIO1(); MM(0); PRIO0(); SBAR();
    // p4: read t0.k1 A m4-7 | stage t2.B.k1 (last read p3) | vmcnt(6)
    LOADA(0, 1, 1);
    STAGE_B(0, 1, ke2);
    SBAR(); WAITLG(); PRIO1(); MM(1); PRIO0();
    WAITV6(); SBAR();
    // p5: read t1.k0 (A m0-3, B) | stage t2.A.k1 (last read p4)
    LOADA(1, 0, 0); LOADB(1, 0);
    STAGE_A(0, 1, ke2);
    SBAR(); WAITLG(); PRIO1(); MM(0); PRIO0(); SBAR();
    // p6: read t1.k0 A m4-7 | stage t3.B.k0 (last read p5)
    LOADA(1, 0, 1);
    STAGE_B(1, 0, ke3);
    SBAR(); WAITLG(); PRIO1(); MM(1); PRIO0(); SBAR();
    // p7: read t1.k1 (A m0-3, B) | stage t3.A.k0 (last read p6)
    LOADA(1, 1, 0); LOADB(1, 1);
    STAGE_A(1, 0, ke3);
    SBAR(); WAITLG(); PRIO1(); MM(0); PRIO0(); SBAR();
    // p8: read t1.k1 A m4-7 | stage t3.B.k1 (last read p7) | vmcnt(6)
    LOADA(1, 1, 1);
    STAGE_B(1, 1, ke3);
    SBAR(); WAITLG(); PRIO1(); MM(1); PRIO0();
    WAITV6(); SBAR();
  }
  asm volatile("s_waitcnt vmcnt(0) lgkmcnt(0)" ::: "memory");
  SBAR();

  // ---- epilogue ----
  const int row0 = bm + wr * 128 + (lane >> 4) * 4;
  const int col0 = bn + wc * 64 + (lane & 15);
#pragma unroll
  for (int m = 0; m < 8; ++m) {
#pragma unroll
    for (int n = 0; n < 4; ++n) {
#pragma unroll
      for (int jj = 0; jj < 4; ++jj) {
        const int rr = row0 + m * 16 + jj;
        const int cc = col0 + n * 16;
        const float v = acc[m][n][jj];
        if constexpr (EPI == 0) {
          ((bf16*)Cv)[(size_t)z * sC + (size_t)rr * ldc + cc] = __float2bfloat16(v);
        } else if constexpr (EPI == 1) {
          ((float*)Cv)[(size_t)z * sC + (size_t)rr * ldc + cc] = v * scale;
        } else if constexpr (EPI == 2) {
          ((float*)Cv)[(size_t)z * sC + (size_t)rr * ldc + cc] =
              v + resid[(size_t)z * sR + (size_t)rr * ldr + cc];
        } else if constexpr (EPI == 3) {
          ((bf16*)Cv)[(size_t)z * sC + (size_t)rr * ldc + cc] =
              __float2bfloat16(gelu_erf(v + bias[cc]));
        } else {
          float* Cf = (float*)Cv + (size_t)z * sC;
          const size_t idx = (size_t)rr * ldc + cc;
          Cf[idx] = Cf[idx] + v + bias[cc];
        }
      }
    }
  }
#undef STAGE_A
#undef STAGE_B
#undef LOADA
#undef LOADB
#undef MM
}

// ---------------- LayerNorm: fp32 in -> bf16 out, row length 1024 ----------
__global__ void ln_kernel(const float* __restrict__ X, const float* __restrict__ gw,
                          const float* __restrict__ bw, bf16* __restrict__ Y) {
  const int row = blockIdx.x, tid = threadIdx.x;
  const float4 xv = *(const float4*)(X + (size_t)row * 1024 + tid * 4);
  float s = xv.x + xv.y + xv.z + xv.w;
  float ss = xv.x * xv.x + xv.y * xv.y + xv.z * xv.z + xv.w * xv.w;
  __shared__ float red[8];
#pragma unroll
  for (int o = 32; o; o >>= 1) {
    s += __shfl_xor(s, o);
    ss += __shfl_xor(ss, o);
  }
  if ((tid & 63) == 0) {
    red[tid >> 6] = s;
    red[4 + (tid >> 6)] = ss;
  }
  __syncthreads();
  s = red[0] + red[1] + red[2] + red[3];
  ss = red[4] + red[5] + red[6] + red[7];
  const float mu = s * (1.f / 1024.f);
  const float var = ss * (1.f / 1024.f) - mu * mu;
  const float rs = rsqrtf(var + 1e-5f);
  const float4 gv = *(const float4*)(gw + tid * 4);
  const float4 bv = *(const float4*)(bw + tid * 4);
  union { ushort4 u; bf16 h[4]; } p;
  p.h[0] = __float2bfloat16((xv.x - mu) * rs * gv.x + bv.x);
  p.h[1] = __float2bfloat16((xv.y - mu) * rs * gv.y + bv.y);
  p.h[2] = __float2bfloat16((xv.z - mu) * rs * gv.z + bv.z);
  p.h[3] = __float2bfloat16((xv.w - mu) * rs * gv.w + bv.w);
  *(ushort4*)(Y + (size_t)row * 1024 + tid * 4) = p.u;
}

// ---------------- Softmax over rows of 2048 fp32 -> bf16 -------------------
__global__ void softmax_kernel(const float* __restrict__ S, bf16* __restrict__ P) {
  const size_t row = blockIdx.x;
  const int tid = threadIdx.x;
  const float4* sp = (const float4*)(S + row * 2048);
  const float4 v0 = sp[tid * 2], v1 = sp[tid * 2 + 1];
  float f[8] = {v0.x, v0.y, v0.z, v0.w, v1.x, v1.y, v1.z, v1.w};
  float m = f[0];
#pragma unroll
  for (int j = 1; j < 8; ++j) m = fmaxf(m, f[j]);
  __shared__ float red[4];
#pragma unroll
  for (int o = 32; o; o >>= 1) m = fmaxf(m, __shfl_xor(m, o));
  if ((tid & 63) == 0) red[tid >> 6] = m;
  __syncthreads();
  m = fmaxf(fmaxf(red[0], red[1]), fmaxf(red[2], red[3]));
  float s = 0.f;
#pragma unroll
  for (int j = 0; j < 8; ++j) {
    f[j] = expf(f[j] - m);
    s += f[j];
  }
#pragma unroll
  for (int o = 32; o; o >>= 1) s += __shfl_xor(s, o);
  __syncthreads();
  if ((tid & 63) == 0) red[tid >> 6] = s;
  __syncthreads();
  s = red[0] + red[1] + red[2] + red[3];
  const float inv = 1.f / s;
  union { uint4 u; bf16 h[8]; } p;
#pragma unroll
  for (int j = 0; j < 8; ++j) p.h[j] = __float2bfloat16(f[j] * inv);
  *(uint4*)(P + row * 2048 + tid * 8) = p.u;
}

// ------- Transpose + convert fp32 W[K][N] -> bf16 WT[rowoff+n][k] ----------
__global__ void transpose_conv(const float* __restrict__ W, bf16* __restrict__ WT,
                               int Nd, int ldT, int rowoff) {
  __shared__ float t[32][33];
  const int tx = threadIdx.x, ty = threadIdx.y;
  const int n0 = blockIdx.x * 32, k0 = blockIdx.y * 32;
#pragma unroll
  for (int j = 0; j < 4; ++j)
    t[ty + 8 * j][tx] = W[(size_t)(k0 + ty + 8 * j) * Nd + n0 + tx];
  __syncthreads();
#pragma unroll
  for (int j = 0; j < 4; ++j)
    WT[(size_t)(rowoff + n0 + ty + 8 * j) * ldT + k0 + tx] =
        __float2bfloat16(t[tx][ty + 8 * j]);
}

// ------- bf16 transpose: dst[c][r] = src[r][c], batched over z -------------
__global__ void transpose_bf16(const bf16* __restrict__ src, bf16* __restrict__ dst,
                               int ldsrc, int lddst, long long zs, long long zd) {
  __shared__ bf16 t[32][33];
  const int z = blockIdx.z;
  src += (size_t)z * zs;
  dst += (size_t)z * zd;
  const int tx = threadIdx.x, ty = threadIdx.y;
  const int c0 = blockIdx.x * 32, r0 = blockIdx.y * 32;
#pragma unroll
  for (int j = 0; j < 4; ++j)
    t[ty + 8 * j][tx] = src[(size_t)(r0 + ty + 8 * j) * ldsrc + c0 + tx];
  __syncthreads();
#pragma unroll
  for (int j = 0; j < 4; ++j)
    dst[(size_t)(c0 + ty + 8 * j) * lddst + r0 + tx] = t[tx][ty + 8 * j];
}

extern "C" void kernel_launch(void* const* d_in, const int* in_sizes, int n_in,
                              void* d_out, int out_size, void* d_ws, size_t ws_size,
                              hipStream_t stream) {
  const float* x = (const float*)d_in[0];
  const float* ln1_g = (const float*)d_in[1];
  const float* ln1_b = (const float*)d_in[2];
  const float* Wq = (const float*)d_in[3];
  const float* Wk = (const float*)d_in[4];
  const float* Wv = (const float*)d_in[5];
  const float* ln2_g = (const float*)d_in[6];
  const float* ln2_b = (const float*)d_in[7];
  const float* W1 = (const float*)d_in[8];
  const float* b1 = (const float*)d_in[9];
  const float* W2 = (const float*)d_in[10];
  const float* b2 = (const float*)d_in[11];
  float* out = (float*)d_out;

  constexpr int B = 8, N = 2048, H = 1024, F = 4096;
  constexpr int M = B * N;  // 16384

  const size_t WqkvTB = (size_t)3 * H * H * 2;
  const size_t W1TB = (size_t)H * F * 2;
  const size_t W2TB = (size_t)H * F * 2;
  const size_t yB = (size_t)M * H * 2;
  const size_t vTB = (size_t)M * H * 2;
  const size_t qkvB = (size_t)M * 3 * H * 2;
  const size_t SB1 = (size_t)N * N * 4;
  const size_t attB1 = (size_t)N * N * 2;
  const size_t hB = (size_t)M * F * 2;
  const size_t fixedB = WqkvTB + W1TB + W2TB + yB + vTB;

  int g = 8;
  for (; g > 1; g >>= 1) {
    size_t R = qkvB + (size_t)g * (SB1 + attB1);
    if (R < hB) R = hB;
    if (fixedB + R <= ws_size) break;
  }

  char* ws = (char*)d_ws;
  size_t o = 0;
  bf16* wqkvT = (bf16*)(ws + o); o += WqkvTB;
  bf16* w1T = (bf16*)(ws + o);   o += W1TB;
  bf16* w2T = (bf16*)(ws + o);   o += W2TB;
  bf16* y = (bf16*)(ws + o);     o += yB;
  bf16* vT = (bf16*)(ws + o);    o += vTB;
  char* Rb = ws + o;
  bf16* qkv = (bf16*)Rb;
  float* S = (float*)(Rb + qkvB);
  bf16* att = (bf16*)(Rb + qkvB + (size_t)g * SB1);
  bf16* h = (bf16*)Rb;  // overlays qkv/S/att after attention is done

  const dim3 tb(32, 8);
  // weight transpose+convert
  transpose_conv<<<dim3(H / 32, H / 32), tb, 0, stream>>>(Wq, wqkvT, H, H, 0);
  transpose_conv<<<dim3(H / 32, H / 32), tb, 0, stream>>>(Wk, wqkvT, H, H, H);
  transpose_conv<<<dim3(H / 32, H / 32), tb, 0, stream>>>(Wv, wqkvT, H, H, 2 * H);
  transpose_conv<<<dim3(F / 32, H / 32), tb, 0, stream>>>(W1, w1T, F, H, 0);
  transpose_conv<<<dim3(H / 32, F / 32), tb, 0, stream>>>(W2, w2T, H, F, 0);

  // LN1
  ln_kernel<<<M, 256, 0, stream>>>(x, ln1_g, ln1_b, y);

  // QKV projection: [M,H] @ WqkvT[3H,H]^T -> qkv [M,3H] bf16
  gemm_nt<0><<<dim3(3 * H / 256, M / 256, 1), 512, 0, stream>>>(
      y, wqkvT, qkv, H, H, H, 3 * H, 0, 0, 0, 1.f, nullptr, nullptr, 0, 0);

  // transpose V per batch: vT[b][d][m]
  transpose_bf16<<<dim3(H / 32, N / 32, B), tb, 0, stream>>>(
      qkv + 2 * H, vT, 3 * H, N, (long long)N * 3 * H, (long long)H * N);

  // attention in groups of g batches
  for (int b0 = 0; b0 < B; b0 += g) {
    const bf16* qb = qkv + (size_t)b0 * N * 3 * H;
    gemm_nt<1><<<dim3(N / 256, N / 256, g), 512, 0, stream>>>(
        qb, qb + H, S, H, 3 * H, 3 * H, N, (long long)N * 3 * H,
        (long long)N * 3 * H, (long long)N * N, 0.03125f, nullptr, nullptr, 0, 0);
    softmax_kernel<<<g * N, 256, 0, stream>>>(S, att);
    gemm_nt<2><<<dim3(H / 256, N / 256, g), 512, 0, stream>>>(
        att, vT + (size_t)b0 * H * N, out + (size_t)b0 * N * H, N, N, N, H,
        (long long)N * N, (long long)H * N, (long long)N * H, 1.f, nullptr,
        x + (size_t)b0 * N * H, (long long)N * H, H);
  }

  // LN2 on x2 (= d_out)
  ln_kernel<<<M, 256, 0, stream>>>(out, ln2_g, ln2_b, y);

  // FFN1: gelu(y @ W1 + b1) -> h bf16 [M,F]
  gemm_nt<3><<<dim3(F / 256, M / 256, 1), 512, 0, stream>>>(
      y, w1T, h, H, H, H, F, 0, 0, 0, 1.f, b1, nullptr, 0, 0);

  // FFN2: out += h @ W2 + b2 (in-place residual on d_out)
  gemm_nt<4><<<dim3(H / 256, M / 256, 1), 512, 0, stream>>>(
      h, w2T, out, F, F, F, H, 0, 0, 0, 1.f, b2, nullptr, 0, 0);
}